// Round 4
// baseline (7253.777 us; speedup 1.0000x reference)
//
#include <hip/hip_runtime.h>
#include <cstdint>
#include <cstddef>

// ---------------------------------------------------------------------------
// JIIF fused pipeline (round 4):
//   - GEMM restructured: A fragments loaded DIRECT from global (per-lane
//     dwordx4, reg ping-pong per ks) -- A never touches LDS. B-only LDS
//     double buffer (2x16KB), stage(kt+1) issued before compute(kt) so the
//     barrier drain is overlapped. XOR-swizzled B slots (0 bank conflicts).
//   - Packed-permuted C store: 8B dwordx2 per (mi,rr) at col p=wn+r*4+ni;
//     permutation folded into next layer's weight transpose (perm flag) and
//     into W4 indexing in l4_combine. X / W0 stay in natural k-order.
//   - XCD-aware (m,n) decode (blocks sharing an m-tile share g%8 == XCD).
// Rows ordered point-major: row = point*4 + shift.
// ---------------------------------------------------------------------------

typedef unsigned short u16;
typedef unsigned int u32;
typedef _Float16 half8 __attribute__((ext_vector_type(8)));
typedef float floatx4 __attribute__((ext_vector_type(4)));
typedef u32 u32x2 __attribute__((ext_vector_type(2)));

__device__ __forceinline__ u16 f2h(float x) {
    _Float16 h = (_Float16)x;
    return __builtin_bit_cast(unsigned short, h);
}
__device__ __forceinline__ float h2f(u16 u) {
    return (float)__builtin_bit_cast(_Float16, u);
}

// async 16B global -> LDS (wave-uniform LDS base + lane*16)
__device__ __forceinline__ void cp_async16(const void* gsrc, void* lds) {
#if defined(__has_builtin) && __has_builtin(__builtin_amdgcn_global_load_lds)
    __builtin_amdgcn_global_load_lds(
        (__attribute__((address_space(1))) void*)(uintptr_t)gsrc,
        (__attribute__((address_space(3))) void*)(uint32_t)(uintptr_t)lds,
        16, 0, 0);
#else
    typedef u32 u32x4 __attribute__((ext_vector_type(4)));
    *(u32x4*)lds = *(const u32x4*)gsrc;
#endif
}

// ---------------- transpose [B][C=128][HW] fp32 -> [B][HW][C] fp16 ----------
__global__ void transpose_chw_hwc(const float* __restrict__ src,
                                  u16* __restrict__ dst, int HW) {
    __shared__ float t[32][33];
    const int b = blockIdx.z;
    const int hw0 = blockIdx.x * 32, c0 = blockIdx.y * 32;
    const float* s = src + (size_t)b * 128 * HW;
    u16* d = dst + (size_t)b * HW * 128;
    const int tx = threadIdx.x, ty = threadIdx.y;
#pragma unroll
    for (int j = 0; j < 4; ++j)
        t[ty + j * 8][tx] = s[(size_t)(c0 + ty + j * 8) * HW + hw0 + tx];
    __syncthreads();
#pragma unroll
    for (int j = 0; j < 4; ++j)
        d[(size_t)(hw0 + ty + j * 8) * 128 + c0 + tx] = f2h(t[tx][ty + j * 8]);
}

// ---------------- weight transpose: W [K x N] fp32 -> Wt [N x K] fp16 -------
// perm!=0: stored k index kk actually holds source channel
//   pi(kk) = (kk & ~63) + (kk&3)*16 + ((kk>>2)&15)   (matches packed C store)
__global__ void prep_wt(const float* __restrict__ W, u16* __restrict__ Wt,
                        int K, int N, int perm) {
    int idx = blockIdx.x * 256 + threadIdx.x;
    if (idx >= N * K) return;
    int nn = idx / K, kk = idx - nn * K;
    int ka = kk;
    if (perm) {
        int s = kk & 63;
        ka = (kk & ~63) + ((s & 3) << 4) + (s >> 2);
    }
    Wt[idx] = f2h(W[(size_t)ka * N + nn]);
}

// ---------------- gather / build X ------------------------------------------
// one wave per point (4 waves/block); lane handles channel pair (2l, 2l+1)
__global__ __launch_bounds__(256) void gather_build(
    const float* __restrict__ coord, const u16* __restrict__ hrT,
    const u16* __restrict__ featT, const u16* __restrict__ lrT,
    u16* __restrict__ X, float* __restrict__ rel, int p0) {
    const int wid = threadIdx.x >> 6, lane = threadIdx.x & 63;
    const int pl = blockIdx.x * 4 + wid;
    const int p = p0 + pl;
    const int b = p >> 16;  // N per batch = 65536
    const float cy = coord[(size_t)p * 2];
    const float cx = coord[(size_t)p * 2 + 1];
    const u32* hr32 = (const u32*)hrT;
    const u32* ft32 = (const u32*)featT;
    const u32* lr32 = (const u32*)lrT;

    // hr sample at unshifted coord (H=W=256)
    float fy = rintf(((cy + 1.0f) * 256.0f - 1.0f) * 0.5f);
    float fx = rintf(((cx + 1.0f) * 256.0f - 1.0f) * 0.5f);
    bool vh = (fy >= 0.0f) && (fy < 256.0f) && (fx >= 0.0f) && (fx < 256.0f);
    int iy = (int)fminf(fmaxf(fy, 0.0f), 255.0f);
    int ix = (int)fminf(fmaxf(fx, 0.0f), 255.0f);
    u32 hrv = hr32[((((size_t)b * 256 + iy) * 256 + ix) * 128 >> 1) + lane];
    if (!vh) hrv = 0u;
    const float hr_lo = h2f((u16)(hrv & 0xffffu));
    const float hr_hi = h2f((u16)(hrv >> 16));

    const size_t rowbase = (size_t)pl * 4;
#pragma unroll
    for (int s = 0; s < 4; ++s) {
        // shift order: s=0:(-1,-1) 1:(-1,+1) 2:(+1,-1) 3:(+1,+1) over (vx,vy)
        float sy = (s & 2) ? 0.015625f : -0.015625f;
        float sx = (s & 1) ? 0.015625f : -0.015625f;
        float gy = rintf(((cy + sy + 1.0f) * 64.0f - 1.0f) * 0.5f);
        float gx = rintf(((cx + sx + 1.0f) * 64.0f - 1.0f) * 0.5f);
        bool v = (gy >= 0.0f) && (gy < 64.0f) && (gx >= 0.0f) && (gx < 64.0f);
        int jy = (int)fminf(fmaxf(gy, 0.0f), 63.0f);
        int jx = (int)fminf(fmaxf(gx, 0.0f), 63.0f);
        size_t g32 = ((((size_t)b * 64 + jy) * 64 + jx) * 128 >> 1) + lane;
        u32 fv = ft32[g32];
        u32 lv = lr32[g32];
        if (!v) { fv = 0u; lv = 0u; }
        u16 d_lo = f2h(hr_lo - h2f((u16)(lv & 0xffffu)));
        u16 d_hi = f2h(hr_hi - h2f((u16)(lv >> 16)));

        u32* xr = (u32*)(X + (rowbase + s) * 384);
        xr[lane] = fv;                                    // q_feat
        xr[64 + lane] = hrv;                              // q_hr
        xr[128 + lane] = (u32)d_lo | ((u32)d_hi << 16);   // q_hr - q_lr

        if (lane == 0) {
            float qcy = v ? (-0.984375f + 0.03125f * (float)jy) : 0.0f;
            float qcx = v ? (-0.984375f + 0.03125f * (float)jx) : 0.0f;
            rel[(rowbase + s) * 2 + 0] = (cy - qcy) * 64.0f;
            rel[(rowbase + s) * 2 + 1] = (cx - qcx) * 64.0f;
        }
    }
}

// ---------------- fused GEMM + bias + ReLU ----------------------------------
// C[M x N] = relu(A[M x K] * Bt[N x K]^T + bias (+ rel-coord rank-2 for L0))
// A fragments direct-from-global (reg ping-pong), B via 2x16KB LDS dbuf with
// stage-before-compute overlap. Output stored packed-permuted (see prep_wt).
// block = 256 (4 waves), BK = 64, grid = mt * nb (1-D).
__global__ __launch_bounds__(256) void gemm_f16(
    const u16* __restrict__ A, const u16* __restrict__ Bt,
    const float* __restrict__ bias, u16* __restrict__ C, int K, int N,
    int lognb, const float* __restrict__ rel, const float* __restrict__ w0tail) {
    __shared__ __align__(16) u16 Bs[2][128 * 64];
    const int tid = threadIdx.x;
    const int lane = tid & 63;
    const int wid = tid >> 6;
    const int r = lane & 15, q = lane >> 4;
    const int wm = (wid & 1) << 6, wn = (wid >> 1) << 6;

    // XCD-aware decode: blocks sharing an m-tile have equal g%8 -> same XCD.
    const int g = blockIdx.x;
    const int n_idx = (g >> 3) & ((1 << lognb) - 1);
    const int m_idx = (g & 7) + ((g >> (3 + lognb)) << 3);
    const int n0 = n_idx << 7;
    const size_t m0 = (size_t)m_idx << 7;

    // B staging: thread covers rows (tid>>3)+32i, slot tid&7; source chunk
    // XOR-swizzled so LDS slot (R, c) holds global chunk c^(R&7).
    const int srow = tid >> 3;
    const int schunk = (tid & 7) ^ (srow & 7);
    const u16* gb = Bt + (size_t)(n0 + srow) * (size_t)K + (schunk << 3);

    auto stageB = [&](int kt, int buf) {
        const u16* gbk = gb + (kt << 6);
        u16* lb = &Bs[buf][tid * 8];
#pragma unroll
        for (int i = 0; i < 4; ++i)
            cp_async16(gbk + (size_t)(i << 5) * K, lb + (i << 11));
    };

    // per-lane A row bases (4 m-tiles); frag (kt,ks) at +kt*64+ks*32 (+q*8 incl)
    const u16* arow[4];
#pragma unroll
    for (int mi = 0; mi < 4; ++mi)
        arow[mi] = A + (m0 + wm + mi * 16 + r) * (size_t)K + (q << 3);

    // B fragment LDS offsets: row wn+ni*16+r, chunk 4ks+q at slot ^(r&7)
    const int bro = (wn + r) << 6;
    const int sl0 = (q ^ (r & 7)) << 3;          // ks=0
    const int sl1 = ((4 ^ q) ^ (r & 7)) << 3;    // ks=1

    floatx4 acc[4][4];
#pragma unroll
    for (int mi = 0; mi < 4; ++mi)
#pragma unroll
        for (int ni = 0; ni < 4; ++ni)
            acc[mi][ni] = (floatx4){0.0f, 0.0f, 0.0f, 0.0f};

    const int nk = K >> 6;
    half8 a0[4], a1[4];
    stageB(0, 0);
#pragma unroll
    for (int mi = 0; mi < 4; ++mi)
        a0[mi] = *(const half8*)(arow[mi]);  // kt=0, ks=0
    __syncthreads();

    for (int kt = 0; kt < nk; ++kt) {
        const int cur = kt & 1;
        if (kt + 1 < nk) stageB(kt + 1, cur ^ 1);
#pragma unroll
        for (int mi = 0; mi < 4; ++mi)
            a1[mi] = *(const half8*)(arow[mi] + (kt << 6) + 32);
        // ks = 0
#pragma unroll
        for (int ni = 0; ni < 4; ++ni) {
            half8 bf = *(const half8*)&Bs[cur][bro + (ni << 10) + sl0];
#pragma unroll
            for (int mi = 0; mi < 4; ++mi)
                acc[mi][ni] = __builtin_amdgcn_mfma_f32_16x16x32_f16(
                    a0[mi], bf, acc[mi][ni], 0, 0, 0);
        }
        if (kt + 1 < nk) {
#pragma unroll
            for (int mi = 0; mi < 4; ++mi)
                a0[mi] = *(const half8*)(arow[mi] + ((kt + 1) << 6));
        }
        // ks = 1
#pragma unroll
        for (int ni = 0; ni < 4; ++ni) {
            half8 bf = *(const half8*)&Bs[cur][bro + (ni << 10) + sl1];
#pragma unroll
            for (int mi = 0; mi < 4; ++mi)
                acc[mi][ni] = __builtin_amdgcn_mfma_f32_16x16x32_f16(
                    a1[mi], bf, acc[mi][ni], 0, 0, 0);
        }
        __syncthreads();  // drains stage+A prefetch, overlapped by compute
    }

    // epilogue: C/D layout col=lane&15 (=r), row=q*4+reg. Packed-permuted
    // store: stored offset r*4+ni holds actual channel ni*16+r (8B dwordx2).
    float bias_v[4], w0a[4], w0b[4];
#pragma unroll
    for (int ni = 0; ni < 4; ++ni) {
        int col = n0 + wn + ni * 16 + r;
        bias_v[ni] = bias[col];
        w0a[ni] = rel ? w0tail[col] : 0.0f;
        w0b[ni] = rel ? w0tail[N + col] : 0.0f;
    }
#pragma unroll
    for (int mi = 0; mi < 4; ++mi) {
#pragma unroll
        for (int rr = 0; rr < 4; ++rr) {
            size_t row = m0 + wm + mi * 16 + q * 4 + rr;
            float rl0 = 0.0f, rl1 = 0.0f;
            if (rel) {
                rl0 = rel[row * 2];
                rl1 = rel[row * 2 + 1];
            }
            u32 pk[2];
#pragma unroll
            for (int h = 0; h < 2; ++h) {
                u32 w = 0;
#pragma unroll
                for (int j = 0; j < 2; ++j) {
                    int ni = h * 2 + j;
                    float v = acc[mi][ni][rr] + bias_v[ni];
                    if (rel) v += rl0 * w0a[ni] + rl1 * w0b[ni];
                    v = fmaxf(v, 0.0f);
                    w |= (u32)f2h(v) << (16 * j);
                }
                pk[h] = w;
            }
            *(u32x2*)(C + row * (size_t)N + n0 + wn + (r << 2)) =
                (u32x2){pk[0], pk[1]};
        }
    }
}

// ---------------- L4 (128 -> 2) + softmax combine ---------------------------
// one wave per point; A3 is packed-permuted -> index W4 through pi()
__global__ __launch_bounds__(256) void l4_combine(
    const u16* __restrict__ A3, const float* __restrict__ W4,
    const float* __restrict__ b4, float* __restrict__ out, int p0) {
    const int wid = threadIdx.x >> 6, lane = threadIdx.x & 63;
    const int pl = blockIdx.x * 4 + wid;
    // stored channels p=2*lane, 2*lane+1 -> actual pi(p)
    const int p2 = lane * 2;
    const int s0 = p2 & 63, bb = p2 & ~63;
    const int k0 = bb + ((s0 & 3) << 4) + (s0 >> 2);
    const int s1 = s0 + 1;
    const int k1 = bb + ((s1 & 3) << 4) + (s1 >> 2);
    const float w00 = W4[k0 * 2], w01 = W4[k0 * 2 + 1];
    const float w10 = W4[k1 * 2], w11 = W4[k1 * 2 + 1];
    float P0[4], P1[4];
#pragma unroll
    for (int s = 0; s < 4; ++s) {
        size_t rowoff = ((size_t)pl * 4 + s) * 128 + p2;
        u32 av = *(const u32*)(A3 + rowoff);
        float a0 = h2f((u16)(av & 0xffffu));
        float a1 = h2f((u16)(av >> 16));
        float d0 = a0 * w00 + a1 * w10;
        float d1 = a0 * w01 + a1 * w11;
#pragma unroll
        for (int m = 32; m >= 1; m >>= 1) {
            d0 += __shfl_xor(d0, m, 64);
            d1 += __shfl_xor(d1, m, 64);
        }
        P0[s] = d0 + b4[0];
        P1[s] = d1 + b4[1];
    }
    if (lane == 0) {
        float mx = fmaxf(fmaxf(P1[0], P1[1]), fmaxf(P1[2], P1[3]));
        float e0 = __expf(P1[0] - mx), e1 = __expf(P1[1] - mx);
        float e2 = __expf(P1[2] - mx), e3 = __expf(P1[3] - mx);
        float se = e0 + e1 + e2 + e3;
        out[p0 + pl] = (P0[0] * e0 + P0[1] * e1 + P0[2] * e2 + P0[3] * e3) / se;
    }
}

// ---------------------------------------------------------------------------
extern "C" void kernel_launch(void* const* d_in, const int* in_sizes, int n_in,
                              void* d_out, int out_size, void* d_ws,
                              size_t ws_size, hipStream_t stream) {
    const float* feat = (const float*)d_in[0];
    const float* coord = (const float*)d_in[1];
    const float* hr = (const float*)d_in[2];
    const float* lr = (const float*)d_in[3];
    const float* W0 = (const float*)d_in[4];
    const float* b0 = (const float*)d_in[5];
    const float* W1 = (const float*)d_in[6];
    const float* b1 = (const float*)d_in[7];
    const float* W2 = (const float*)d_in[8];
    const float* b2 = (const float*)d_in[9];
    const float* W3 = (const float*)d_in[10];
    const float* b3 = (const float*)d_in[11];
    const float* W4 = (const float*)d_in[12];
    const float* b4 = (const float*)d_in[13];
    float* out = (float*)d_out;

    char* base = (char*)d_ws;
    size_t off = 0;
    auto carve = [&](size_t bytes) -> char* {
        char* p = base + off;
        off += (bytes + 255) & ~(size_t)255;
        return p;
    };

    u16* hrT = (u16*)carve(4ull * 65536 * 128 * 2);   // [4][256][256][128] f16
    u16* featT = (u16*)carve(4ull * 4096 * 128 * 2);  // [4][64][64][128] f16
    u16* lrT = (u16*)carve(4ull * 4096 * 128 * 2);
    u16* Wt0 = (u16*)carve(1024ull * 384 * 2);        // [N][K] f16
    u16* Wt1 = (u16*)carve(512ull * 1024 * 2);
    u16* Wt2 = (u16*)carve(256ull * 512 * 2);
    u16* Wt3 = (u16*)carve(128ull * 256 * 2);
    const size_t fixed = off;

    // chunking: per-row footprint with aliasing:
    //   R1 = max(X 768, A1 1024) = 1024 ; rel = 8 ; R2 = A0 2048 >= A2+A3 768
    const size_t R = 1048576ull;  // 262144 points * 4 shifts
    int c = 1;
    for (; c < 8192; c *= 2) {
        size_t Rc = R / c;
        size_t need = fixed;
        size_t sizes[3] = {Rc * 1024, Rc * 8, Rc * 2048};
        for (int i = 0; i < 3; ++i) need += (sizes[i] + 255) & ~(size_t)255;
        if (need <= ws_size) break;
    }
    const size_t Rc = R / c;
    const int Pc = (int)(262144 / c);

    char* R1 = carve(Rc * 1024);
    float* rel = (float*)carve(Rc * 8);
    char* R2 = carve(Rc * 2048);
    u16* X = (u16*)R1;                   // [Rc][384] f16 (dead after L0)
    u16* A1 = (u16*)R1;                  // [Rc][512]  (overwrites X in L1)
    u16* A0 = (u16*)R2;                  // [Rc][1024] (dead after L1)
    u16* A2 = (u16*)R2;                  // [Rc][256]  (overwrites A0 in L2)
    u16* A3 = (u16*)(R2 + Rc * 512);     // [Rc][128]  (disjoint from A2)

    // prep (once per call). W1/W2/W3 get the pi() k-permutation (their A comes
    // from a packed-permuted GEMM output); W0 reads natural-order X.
    transpose_chw_hwc<<<dim3(2048, 4, 4), dim3(32, 8), 0, stream>>>(hr, hrT, 65536);
    transpose_chw_hwc<<<dim3(128, 4, 4), dim3(32, 8), 0, stream>>>(feat, featT, 4096);
    transpose_chw_hwc<<<dim3(128, 4, 4), dim3(32, 8), 0, stream>>>(lr, lrT, 4096);
    prep_wt<<<(1024 * 384 + 255) / 256, 256, 0, stream>>>(W0, Wt0, 384, 1024, 0);
    prep_wt<<<(512 * 1024 + 255) / 256, 256, 0, stream>>>(W1, Wt1, 1024, 512, 1);
    prep_wt<<<(256 * 512 + 255) / 256, 256, 0, stream>>>(W2, Wt2, 512, 256, 1);
    prep_wt<<<(128 * 256 + 255) / 256, 256, 0, stream>>>(W3, Wt3, 256, 128, 1);

    const int mt = (int)(Rc / 128);  // multiple of 8 for all expected c
    for (int ci = 0; ci < c; ++ci) {
        const int p0 = ci * Pc;
        gather_build<<<Pc / 4, 256, 0, stream>>>(coord, hrT, featT, lrT, X, rel, p0);
        gemm_f16<<<mt * 8, 256, 0, stream>>>(X, Wt0, b0, A0, 384, 1024, 3, rel,
                                             W0 + 384 * 1024);
        gemm_f16<<<mt * 4, 256, 0, stream>>>(A0, Wt1, b1, A1, 1024, 512, 2,
                                             nullptr, nullptr);
        gemm_f16<<<mt * 2, 256, 0, stream>>>(A1, Wt2, b2, A2, 512, 256, 1,
                                             nullptr, nullptr);
        gemm_f16<<<mt * 1, 256, 0, stream>>>(A2, Wt3, b3, A3, 256, 128, 0,
                                             nullptr, nullptr);
        l4_combine<<<Pc / 4, 256, 0, stream>>>(A3, W4, b4, out, p0);
    }
}

// Round 5
// 4573.479 us; speedup vs baseline: 1.5861x; 1.5861x over previous
//
#include <hip/hip_runtime.h>
#include <cstdint>
#include <cstddef>

// ---------------------------------------------------------------------------
// JIIF fused pipeline (round 5):
//   - GEMM core = round-3 structure (A+B through LDS, XOR-swizzle, XCD-aware
//     decode) + asymmetric prefetch:
//       A: 2x16KB LDS double-buffer, global_load_lds DMA for kt+1 issued
//          before compute(kt) -> barrier vmcnt drain overlapped by compute.
//       B: single 16KB LDS, register-staged (dwordx4 -> regs at kt start,
//          ds_write_b128 after the post-compute barrier). +16 VGPR only.
//     LDS 48KB -> 3 blocks/CU kept.
//   - Packed-permuted 8B C-store (round 4), perm folded into next layer's
//     weight transpose and into W4 indexing in l4_combine.
// Rows ordered point-major: row = point*4 + shift.
// ---------------------------------------------------------------------------

typedef unsigned short u16;
typedef unsigned int u32;
typedef _Float16 half8 __attribute__((ext_vector_type(8)));
typedef float floatx4 __attribute__((ext_vector_type(4)));
typedef u32 u32x2 __attribute__((ext_vector_type(2)));
typedef u32 u32x4 __attribute__((ext_vector_type(4)));

__device__ __forceinline__ u16 f2h(float x) {
    _Float16 h = (_Float16)x;
    return __builtin_bit_cast(unsigned short, h);
}
__device__ __forceinline__ float h2f(u16 u) {
    return (float)__builtin_bit_cast(_Float16, u);
}

// async 16B global -> LDS (wave-uniform LDS base + lane*16)
__device__ __forceinline__ void cp_async16(const void* gsrc, void* lds) {
#if defined(__has_builtin) && __has_builtin(__builtin_amdgcn_global_load_lds)
    __builtin_amdgcn_global_load_lds(
        (__attribute__((address_space(1))) void*)(uintptr_t)gsrc,
        (__attribute__((address_space(3))) void*)(uint32_t)(uintptr_t)lds,
        16, 0, 0);
#else
    *(u32x4*)lds = *(const u32x4*)gsrc;
#endif
}

// ---------------- transpose [B][C=128][HW] fp32 -> [B][HW][C] fp16 ----------
__global__ void transpose_chw_hwc(const float* __restrict__ src,
                                  u16* __restrict__ dst, int HW) {
    __shared__ float t[32][33];
    const int b = blockIdx.z;
    const int hw0 = blockIdx.x * 32, c0 = blockIdx.y * 32;
    const float* s = src + (size_t)b * 128 * HW;
    u16* d = dst + (size_t)b * HW * 128;
    const int tx = threadIdx.x, ty = threadIdx.y;
#pragma unroll
    for (int j = 0; j < 4; ++j)
        t[ty + j * 8][tx] = s[(size_t)(c0 + ty + j * 8) * HW + hw0 + tx];
    __syncthreads();
#pragma unroll
    for (int j = 0; j < 4; ++j)
        d[(size_t)(hw0 + ty + j * 8) * 128 + c0 + tx] = f2h(t[tx][ty + j * 8]);
}

// ---------------- weight transpose: W [K x N] fp32 -> Wt [N x K] fp16 -------
// perm!=0: stored k index kk holds source channel
//   pi(kk) = (kk & ~63) + (kk&3)*16 + ((kk>>2)&15)   (matches packed C store)
__global__ void prep_wt(const float* __restrict__ W, u16* __restrict__ Wt,
                        int K, int N, int perm) {
    int idx = blockIdx.x * 256 + threadIdx.x;
    if (idx >= N * K) return;
    int nn = idx / K, kk = idx - nn * K;
    int ka = kk;
    if (perm) {
        int s = kk & 63;
        ka = (kk & ~63) + ((s & 3) << 4) + (s >> 2);
    }
    Wt[idx] = f2h(W[(size_t)ka * N + nn]);
}

// ---------------- gather / build X ------------------------------------------
// one wave per point (4 waves/block); lane handles channel pair (2l, 2l+1)
__global__ __launch_bounds__(256) void gather_build(
    const float* __restrict__ coord, const u16* __restrict__ hrT,
    const u16* __restrict__ featT, const u16* __restrict__ lrT,
    u16* __restrict__ X, float* __restrict__ rel, int p0) {
    const int wid = threadIdx.x >> 6, lane = threadIdx.x & 63;
    const int pl = blockIdx.x * 4 + wid;
    const int p = p0 + pl;
    const int b = p >> 16;  // N per batch = 65536
    const float cy = coord[(size_t)p * 2];
    const float cx = coord[(size_t)p * 2 + 1];
    const u32* hr32 = (const u32*)hrT;
    const u32* ft32 = (const u32*)featT;
    const u32* lr32 = (const u32*)lrT;

    // hr sample at unshifted coord (H=W=256)
    float fy = rintf(((cy + 1.0f) * 256.0f - 1.0f) * 0.5f);
    float fx = rintf(((cx + 1.0f) * 256.0f - 1.0f) * 0.5f);
    bool vh = (fy >= 0.0f) && (fy < 256.0f) && (fx >= 0.0f) && (fx < 256.0f);
    int iy = (int)fminf(fmaxf(fy, 0.0f), 255.0f);
    int ix = (int)fminf(fmaxf(fx, 0.0f), 255.0f);
    u32 hrv = hr32[((((size_t)b * 256 + iy) * 256 + ix) * 128 >> 1) + lane];
    if (!vh) hrv = 0u;
    const float hr_lo = h2f((u16)(hrv & 0xffffu));
    const float hr_hi = h2f((u16)(hrv >> 16));

    const size_t rowbase = (size_t)pl * 4;
#pragma unroll
    for (int s = 0; s < 4; ++s) {
        // shift order: s=0:(-1,-1) 1:(-1,+1) 2:(+1,-1) 3:(+1,+1) over (vx,vy)
        float sy = (s & 2) ? 0.015625f : -0.015625f;
        float sx = (s & 1) ? 0.015625f : -0.015625f;
        float gy = rintf(((cy + sy + 1.0f) * 64.0f - 1.0f) * 0.5f);
        float gx = rintf(((cx + sx + 1.0f) * 64.0f - 1.0f) * 0.5f);
        bool v = (gy >= 0.0f) && (gy < 64.0f) && (gx >= 0.0f) && (gx < 64.0f);
        int jy = (int)fminf(fmaxf(gy, 0.0f), 63.0f);
        int jx = (int)fminf(fmaxf(gx, 0.0f), 63.0f);
        size_t g32 = ((((size_t)b * 64 + jy) * 64 + jx) * 128 >> 1) + lane;
        u32 fv = ft32[g32];
        u32 lv = lr32[g32];
        if (!v) { fv = 0u; lv = 0u; }
        u16 d_lo = f2h(hr_lo - h2f((u16)(lv & 0xffffu)));
        u16 d_hi = f2h(hr_hi - h2f((u16)(lv >> 16)));

        u32* xr = (u32*)(X + (rowbase + s) * 384);
        xr[lane] = fv;                                    // q_feat
        xr[64 + lane] = hrv;                              // q_hr
        xr[128 + lane] = (u32)d_lo | ((u32)d_hi << 16);   // q_hr - q_lr

        if (lane == 0) {
            float qcy = v ? (-0.984375f + 0.03125f * (float)jy) : 0.0f;
            float qcx = v ? (-0.984375f + 0.03125f * (float)jx) : 0.0f;
            rel[(rowbase + s) * 2 + 0] = (cy - qcy) * 64.0f;
            rel[(rowbase + s) * 2 + 1] = (cx - qcx) * 64.0f;
        }
    }
}

// ---------------- fused GEMM + bias + ReLU ----------------------------------
// C[M x N] = relu(A[M x K] * Bt[N x K]^T + bias (+ rel-coord rank-2 for L0))
// A: LDS dbuf via DMA prefetch; B: reg-staged single LDS buffer.
// block = 256 (4 waves), BK = 64, grid = mt * nb (1-D).
__global__ __launch_bounds__(256) void gemm_f16(
    const u16* __restrict__ A, const u16* __restrict__ Bt,
    const float* __restrict__ bias, u16* __restrict__ C, int K, int N,
    int lognb, const float* __restrict__ rel, const float* __restrict__ w0tail) {
    __shared__ __align__(16) u16 As[2][128 * 64];
    __shared__ __align__(16) u16 Bs[128 * 64];
    const int tid = threadIdx.x;
    const int lane = tid & 63;
    const int wid = tid >> 6;
    const int r = lane & 15, q = lane >> 4;
    const int wm = (wid & 1) << 6, wn = (wid >> 1) << 6;

    // XCD-aware decode: blocks sharing an m-tile have equal g%8 -> same XCD.
    const int g = blockIdx.x;
    const int n_idx = (g >> 3) & ((1 << lognb) - 1);
    const int m_idx = (g & 7) + ((g >> (3 + lognb)) << 3);
    const int n0 = n_idx << 7;
    const size_t m0 = (size_t)m_idx << 7;

    // staging: thread covers rows (tid>>3)+32i, LDS slot tid&7; source chunk
    // XOR-swizzled so LDS slot (R, c) holds global chunk c^(R&7).
    const int srow = tid >> 3;
    const int schunk = (tid & 7) ^ (srow & 7);
    const u16* ga = A + (m0 + (size_t)srow) * (size_t)K + (schunk << 3);
    const u16* gb = Bt + (size_t)(n0 + srow) * (size_t)K + (schunk << 3);

    auto stageA = [&](int kt, int buf) {
        const u16* gak = ga + (kt << 6);
        u16* la = &As[buf][tid * 8];
#pragma unroll
        for (int i = 0; i < 4; ++i)
            cp_async16(gak + (size_t)(i << 5) * K, la + (i << 11));
    };

    u32x4 breg[4];
    auto loadB = [&](int kt) {
        const u16* gbk = gb + (kt << 6);
#pragma unroll
        for (int i = 0; i < 4; ++i)
            breg[i] = *(const u32x4*)(gbk + (size_t)(i << 5) * K);
    };
    auto writeB = [&]() {
        u16* lb = &Bs[tid * 8];
#pragma unroll
        for (int i = 0; i < 4; ++i)
            *(u32x4*)(lb + (i << 11)) = breg[i];
    };

    // fragment read offsets: row R, global chunk j at slot j^(r&7)
    const int cx = (q ^ (r & 7)) << 3;  // elements; ks toggles chunk bit 2
    const int arow = (wm + r) << 6, brow = (wn + r) << 6;

    floatx4 acc[4][4];
#pragma unroll
    for (int mi = 0; mi < 4; ++mi)
#pragma unroll
        for (int ni = 0; ni < 4; ++ni)
            acc[mi][ni] = (floatx4){0.0f, 0.0f, 0.0f, 0.0f};

    const int nk = K >> 6;
    // prologue: tile 0
    stageA(0, 0);
    loadB(0);
    writeB();
    __syncthreads();  // A(0) DMA + B(0) ds_write visible

    for (int kt = 0; kt < nk; ++kt) {
        const int cur = kt & 1;
        const bool pf = (kt + 1 < nk);
        if (pf) {
            stageA(kt + 1, cur ^ 1);  // DMA into other buffer, no reg dep
            loadB(kt + 1);            // into regs, consumed after next barrier
        }
#pragma unroll
        for (int ks = 0; ks < 2; ++ks) {
            half8 af[4], bf[4];
#pragma unroll
            for (int mi = 0; mi < 4; ++mi)
                af[mi] = *(const half8*)&As[cur][arow + (mi << 10) + (cx ^ (ks << 5))];
#pragma unroll
            for (int ni = 0; ni < 4; ++ni)
                bf[ni] = *(const half8*)&Bs[brow + (ni << 10) + (cx ^ (ks << 5))];
#pragma unroll
            for (int mi = 0; mi < 4; ++mi)
#pragma unroll
                for (int ni = 0; ni < 4; ++ni)
                    acc[mi][ni] = __builtin_amdgcn_mfma_f32_16x16x32_f16(
                        af[mi], bf[ni], acc[mi][ni], 0, 0, 0);
        }
        if (pf) {
            __syncthreads();  // all waves done reading Bs(kt); drain overlapped
            writeB();         // Bs <- B(kt+1)
            __syncthreads();  // Bs(kt+1) + As[cur^1] resident
        }
    }

    // epilogue: C/D layout col=lane&15 (=r), row=q*4+reg. Packed-permuted
    // store: stored offset r*4+ni holds actual channel ni*16+r (8B dwordx2).
    float bias_v[4], w0a[4], w0b[4];
#pragma unroll
    for (int ni = 0; ni < 4; ++ni) {
        int col = n0 + wn + ni * 16 + r;
        bias_v[ni] = bias[col];
        w0a[ni] = rel ? w0tail[col] : 0.0f;
        w0b[ni] = rel ? w0tail[N + col] : 0.0f;
    }
#pragma unroll
    for (int mi = 0; mi < 4; ++mi) {
#pragma unroll
        for (int rr = 0; rr < 4; ++rr) {
            size_t row = m0 + wm + mi * 16 + q * 4 + rr;
            float rl0 = 0.0f, rl1 = 0.0f;
            if (rel) {
                rl0 = rel[row * 2];
                rl1 = rel[row * 2 + 1];
            }
            u32 pk[2];
#pragma unroll
            for (int h = 0; h < 2; ++h) {
                u32 w = 0;
#pragma unroll
                for (int j = 0; j < 2; ++j) {
                    int ni = h * 2 + j;
                    float v = acc[mi][ni][rr] + bias_v[ni];
                    if (rel) v += rl0 * w0a[ni] + rl1 * w0b[ni];
                    v = fmaxf(v, 0.0f);
                    w |= (u32)f2h(v) << (16 * j);
                }
                pk[h] = w;
            }
            *(u32x2*)(C + row * (size_t)N + n0 + wn + (r << 2)) =
                (u32x2){pk[0], pk[1]};
        }
    }
}

// ---------------- L4 (128 -> 2) + softmax combine ---------------------------
// one wave per point; A3 is packed-permuted -> index W4 through pi()
__global__ __launch_bounds__(256) void l4_combine(
    const u16* __restrict__ A3, const float* __restrict__ W4,
    const float* __restrict__ b4, float* __restrict__ out, int p0) {
    const int wid = threadIdx.x >> 6, lane = threadIdx.x & 63;
    const int pl = blockIdx.x * 4 + wid;
    // stored channels p=2*lane, 2*lane+1 -> actual pi(p)
    const int p2 = lane * 2;
    const int s0 = p2 & 63, bb = p2 & ~63;
    const int k0 = bb + ((s0 & 3) << 4) + (s0 >> 2);
    const int s1 = s0 + 1;
    const int k1 = bb + ((s1 & 3) << 4) + (s1 >> 2);
    const float w00 = W4[k0 * 2], w01 = W4[k0 * 2 + 1];
    const float w10 = W4[k1 * 2], w11 = W4[k1 * 2 + 1];
    float P0[4], P1[4];
#pragma unroll
    for (int s = 0; s < 4; ++s) {
        size_t rowoff = ((size_t)pl * 4 + s) * 128 + p2;
        u32 av = *(const u32*)(A3 + rowoff);
        float a0 = h2f((u16)(av & 0xffffu));
        float a1 = h2f((u16)(av >> 16));
        float d0 = a0 * w00 + a1 * w10;
        float d1 = a0 * w01 + a1 * w11;
#pragma unroll
        for (int m = 32; m >= 1; m >>= 1) {
            d0 += __shfl_xor(d0, m, 64);
            d1 += __shfl_xor(d1, m, 64);
        }
        P0[s] = d0 + b4[0];
        P1[s] = d1 + b4[1];
    }
    if (lane == 0) {
        float mx = fmaxf(fmaxf(P1[0], P1[1]), fmaxf(P1[2], P1[3]));
        float e0 = __expf(P1[0] - mx), e1 = __expf(P1[1] - mx);
        float e2 = __expf(P1[2] - mx), e3 = __expf(P1[3] - mx);
        float se = e0 + e1 + e2 + e3;
        out[p0 + pl] = (P0[0] * e0 + P0[1] * e1 + P0[2] * e2 + P0[3] * e3) / se;
    }
}

// ---------------------------------------------------------------------------
extern "C" void kernel_launch(void* const* d_in, const int* in_sizes, int n_in,
                              void* d_out, int out_size, void* d_ws,
                              size_t ws_size, hipStream_t stream) {
    const float* feat = (const float*)d_in[0];
    const float* coord = (const float*)d_in[1];
    const float* hr = (const float*)d_in[2];
    const float* lr = (const float*)d_in[3];
    const float* W0 = (const float*)d_in[4];
    const float* b0 = (const float*)d_in[5];
    const float* W1 = (const float*)d_in[6];
    const float* b1 = (const float*)d_in[7];
    const float* W2 = (const float*)d_in[8];
    const float* b2 = (const float*)d_in[9];
    const float* W3 = (const float*)d_in[10];
    const float* b3 = (const float*)d_in[11];
    const float* W4 = (const float*)d_in[12];
    const float* b4 = (const float*)d_in[13];
    float* out = (float*)d_out;

    char* base = (char*)d_ws;
    size_t off = 0;
    auto carve = [&](size_t bytes) -> char* {
        char* p = base + off;
        off += (bytes + 255) & ~(size_t)255;
        return p;
    };

    u16* hrT = (u16*)carve(4ull * 65536 * 128 * 2);   // [4][256][256][128] f16
    u16* featT = (u16*)carve(4ull * 4096 * 128 * 2);  // [4][64][64][128] f16
    u16* lrT = (u16*)carve(4ull * 4096 * 128 * 2);
    u16* Wt0 = (u16*)carve(1024ull * 384 * 2);        // [N][K] f16
    u16* Wt1 = (u16*)carve(512ull * 1024 * 2);
    u16* Wt2 = (u16*)carve(256ull * 512 * 2);
    u16* Wt3 = (u16*)carve(128ull * 256 * 2);
    const size_t fixed = off;

    // chunking: per-row footprint with aliasing:
    //   R1 = max(X 768, A1 1024) = 1024 ; rel = 8 ; R2 = A0 2048 >= A2+A3 768
    const size_t R = 1048576ull;  // 262144 points * 4 shifts
    int c = 1;
    for (; c < 8192; c *= 2) {
        size_t Rc = R / c;
        size_t need = fixed;
        size_t sizes[3] = {Rc * 1024, Rc * 8, Rc * 2048};
        for (int i = 0; i < 3; ++i) need += (sizes[i] + 255) & ~(size_t)255;
        if (need <= ws_size) break;
    }
    const size_t Rc = R / c;
    const int Pc = (int)(262144 / c);

    char* R1 = carve(Rc * 1024);
    float* rel = (float*)carve(Rc * 8);
    char* R2 = carve(Rc * 2048);
    u16* X = (u16*)R1;                   // [Rc][384] f16 (dead after L0)
    u16* A1 = (u16*)R1;                  // [Rc][512]  (overwrites X in L1)
    u16* A0 = (u16*)R2;                  // [Rc][1024] (dead after L1)
    u16* A2 = (u16*)R2;                  // [Rc][256]  (overwrites A0 in L2)
    u16* A3 = (u16*)(R2 + Rc * 512);     // [Rc][128]  (disjoint from A2)

    // prep (once per call). W1/W2/W3 get the pi() k-permutation (their A comes
    // from a packed-permuted GEMM output); W0 reads natural-order X.
    transpose_chw_hwc<<<dim3(2048, 4, 4), dim3(32, 8), 0, stream>>>(hr, hrT, 65536);
    transpose_chw_hwc<<<dim3(128, 4, 4), dim3(32, 8), 0, stream>>>(feat, featT, 4096);
    transpose_chw_hwc<<<dim3(128, 4, 4), dim3(32, 8), 0, stream>>>(lr, lrT, 4096);
    prep_wt<<<(1024 * 384 + 255) / 256, 256, 0, stream>>>(W0, Wt0, 384, 1024, 0);
    prep_wt<<<(512 * 1024 + 255) / 256, 256, 0, stream>>>(W1, Wt1, 1024, 512, 1);
    prep_wt<<<(256 * 512 + 255) / 256, 256, 0, stream>>>(W2, Wt2, 512, 256, 1);
    prep_wt<<<(128 * 256 + 255) / 256, 256, 0, stream>>>(W3, Wt3, 256, 128, 1);

    const int mt = (int)(Rc / 128);  // multiple of 8 for all expected c
    for (int ci = 0; ci < c; ++ci) {
        const int p0 = ci * Pc;
        gather_build<<<Pc / 4, 256, 0, stream>>>(coord, hrT, featT, lrT, X, rel, p0);
        gemm_f16<<<mt * 8, 256, 0, stream>>>(X, Wt0, b0, A0, 384, 1024, 3, rel,
                                             W0 + 384 * 1024);
        gemm_f16<<<mt * 4, 256, 0, stream>>>(A0, Wt1, b1, A1, 1024, 512, 2,
                                             nullptr, nullptr);
        gemm_f16<<<mt * 2, 256, 0, stream>>>(A1, Wt2, b2, A2, 512, 256, 1,
                                             nullptr, nullptr);
        gemm_f16<<<mt * 1, 256, 0, stream>>>(A2, Wt3, b3, A3, 256, 128, 0,
                                             nullptr, nullptr);
        l4_combine<<<Pc / 4, 256, 0, stream>>>(A3, W4, b4, out, p0);
    }
}

// Round 6
// 3935.970 us; speedup vs baseline: 1.8429x; 1.1620x over previous
//
#include <hip/hip_runtime.h>
#include <cstdint>
#include <cstddef>

// ---------------------------------------------------------------------------
// JIIF fused pipeline (round 6):
//   - GEMM = round-5 asymmetric prefetch (A: 2x16KB LDS dbuf via
//     global_load_lds DMA; B: reg-staged single 16KB buffer) with:
//       * __launch_bounds__(256, 3): force 3 waves/SIMD (round 5 slipped to 2
//         at VGPR 108+64acc=172; occupancy 22% -> target ~31%)
//       * 32-bit A/B/C offsets (base + u32 voffset) to shave address VGPRs
//       * loadB issued before stageA (writeB waits only breg, not DMA queue)
//   - XOR-swizzled LDS (0 conflicts), XCD-aware decode, packed-permuted 8B
//     C-store with perm folded into next layer's weights / W4 indexing.
// Rows ordered point-major: row = point*4 + shift.
// ---------------------------------------------------------------------------

typedef unsigned short u16;
typedef unsigned int u32;
typedef _Float16 half8 __attribute__((ext_vector_type(8)));
typedef float floatx4 __attribute__((ext_vector_type(4)));
typedef u32 u32x2 __attribute__((ext_vector_type(2)));
typedef u32 u32x4 __attribute__((ext_vector_type(4)));

__device__ __forceinline__ u16 f2h(float x) {
    _Float16 h = (_Float16)x;
    return __builtin_bit_cast(unsigned short, h);
}
__device__ __forceinline__ float h2f(u16 u) {
    return (float)__builtin_bit_cast(_Float16, u);
}

// async 16B global -> LDS (wave-uniform LDS base + lane*16)
__device__ __forceinline__ void cp_async16(const void* gsrc, void* lds) {
#if defined(__has_builtin) && __has_builtin(__builtin_amdgcn_global_load_lds)
    __builtin_amdgcn_global_load_lds(
        (__attribute__((address_space(1))) void*)(uintptr_t)gsrc,
        (__attribute__((address_space(3))) void*)(uint32_t)(uintptr_t)lds,
        16, 0, 0);
#else
    *(u32x4*)lds = *(const u32x4*)gsrc;
#endif
}

// ---------------- transpose [B][C=128][HW] fp32 -> [B][HW][C] fp16 ----------
__global__ void transpose_chw_hwc(const float* __restrict__ src,
                                  u16* __restrict__ dst, int HW) {
    __shared__ float t[32][33];
    const int b = blockIdx.z;
    const int hw0 = blockIdx.x * 32, c0 = blockIdx.y * 32;
    const float* s = src + (size_t)b * 128 * HW;
    u16* d = dst + (size_t)b * HW * 128;
    const int tx = threadIdx.x, ty = threadIdx.y;
#pragma unroll
    for (int j = 0; j < 4; ++j)
        t[ty + j * 8][tx] = s[(size_t)(c0 + ty + j * 8) * HW + hw0 + tx];
    __syncthreads();
#pragma unroll
    for (int j = 0; j < 4; ++j)
        d[(size_t)(hw0 + ty + j * 8) * 128 + c0 + tx] = f2h(t[tx][ty + j * 8]);
}

// ---------------- weight transpose: W [K x N] fp32 -> Wt [N x K] fp16 -------
// perm!=0: stored k index kk holds source channel
//   pi(kk) = (kk & ~63) + (kk&3)*16 + ((kk>>2)&15)   (matches packed C store)
__global__ void prep_wt(const float* __restrict__ W, u16* __restrict__ Wt,
                        int K, int N, int perm) {
    int idx = blockIdx.x * 256 + threadIdx.x;
    if (idx >= N * K) return;
    int nn = idx / K, kk = idx - nn * K;
    int ka = kk;
    if (perm) {
        int s = kk & 63;
        ka = (kk & ~63) + ((s & 3) << 4) + (s >> 2);
    }
    Wt[idx] = f2h(W[(size_t)ka * N + nn]);
}

// ---------------- gather / build X ------------------------------------------
// one wave per point (4 waves/block); lane handles channel pair (2l, 2l+1)
__global__ __launch_bounds__(256) void gather_build(
    const float* __restrict__ coord, const u16* __restrict__ hrT,
    const u16* __restrict__ featT, const u16* __restrict__ lrT,
    u16* __restrict__ X, float* __restrict__ rel, int p0) {
    const int wid = threadIdx.x >> 6, lane = threadIdx.x & 63;
    const int pl = blockIdx.x * 4 + wid;
    const int p = p0 + pl;
    const int b = p >> 16;  // N per batch = 65536
    const float cy = coord[(size_t)p * 2];
    const float cx = coord[(size_t)p * 2 + 1];
    const u32* hr32 = (const u32*)hrT;
    const u32* ft32 = (const u32*)featT;
    const u32* lr32 = (const u32*)lrT;

    // hr sample at unshifted coord (H=W=256)
    float fy = rintf(((cy + 1.0f) * 256.0f - 1.0f) * 0.5f);
    float fx = rintf(((cx + 1.0f) * 256.0f - 1.0f) * 0.5f);
    bool vh = (fy >= 0.0f) && (fy < 256.0f) && (fx >= 0.0f) && (fx < 256.0f);
    int iy = (int)fminf(fmaxf(fy, 0.0f), 255.0f);
    int ix = (int)fminf(fmaxf(fx, 0.0f), 255.0f);
    u32 hrv = hr32[((((size_t)b * 256 + iy) * 256 + ix) * 128 >> 1) + lane];
    if (!vh) hrv = 0u;
    const float hr_lo = h2f((u16)(hrv & 0xffffu));
    const float hr_hi = h2f((u16)(hrv >> 16));

    const size_t rowbase = (size_t)pl * 4;
#pragma unroll
    for (int s = 0; s < 4; ++s) {
        // shift order: s=0:(-1,-1) 1:(-1,+1) 2:(+1,-1) 3:(+1,+1) over (vx,vy)
        float sy = (s & 2) ? 0.015625f : -0.015625f;
        float sx = (s & 1) ? 0.015625f : -0.015625f;
        float gy = rintf(((cy + sy + 1.0f) * 64.0f - 1.0f) * 0.5f);
        float gx = rintf(((cx + sx + 1.0f) * 64.0f - 1.0f) * 0.5f);
        bool v = (gy >= 0.0f) && (gy < 64.0f) && (gx >= 0.0f) && (gx < 64.0f);
        int jy = (int)fminf(fmaxf(gy, 0.0f), 63.0f);
        int jx = (int)fminf(fmaxf(gx, 0.0f), 63.0f);
        size_t g32 = ((((size_t)b * 64 + jy) * 64 + jx) * 128 >> 1) + lane;
        u32 fv = ft32[g32];
        u32 lv = lr32[g32];
        if (!v) { fv = 0u; lv = 0u; }
        u16 d_lo = f2h(hr_lo - h2f((u16)(lv & 0xffffu)));
        u16 d_hi = f2h(hr_hi - h2f((u16)(lv >> 16)));

        u32* xr = (u32*)(X + (rowbase + s) * 384);
        xr[lane] = fv;                                    // q_feat
        xr[64 + lane] = hrv;                              // q_hr
        xr[128 + lane] = (u32)d_lo | ((u32)d_hi << 16);   // q_hr - q_lr

        if (lane == 0) {
            float qcy = v ? (-0.984375f + 0.03125f * (float)jy) : 0.0f;
            float qcx = v ? (-0.984375f + 0.03125f * (float)jx) : 0.0f;
            rel[(rowbase + s) * 2 + 0] = (cy - qcy) * 64.0f;
            rel[(rowbase + s) * 2 + 1] = (cx - qcx) * 64.0f;
        }
    }
}

// ---------------- fused GEMM + bias + ReLU ----------------------------------
// C[M x N] = relu(A[M x K] * Bt[N x K]^T + bias (+ rel-coord rank-2 for L0))
// A: LDS dbuf via DMA prefetch; B: reg-staged single LDS buffer.
// block = 256 (4 waves, 3 blocks/CU forced), BK = 64, grid = mt * nb (1-D).
__global__ __launch_bounds__(256, 3) void gemm_f16(
    const u16* __restrict__ A, const u16* __restrict__ Bt,
    const float* __restrict__ bias, u16* __restrict__ C, int K, int N,
    int lognb, const float* __restrict__ rel, const float* __restrict__ w0tail) {
    __shared__ __align__(16) u16 As[2][128 * 64];
    __shared__ __align__(16) u16 Bs[128 * 64];
    const int tid = threadIdx.x;
    const int lane = tid & 63;
    const int wid = tid >> 6;
    const int r = lane & 15, q = lane >> 4;
    const int wm = (wid & 1) << 6, wn = (wid >> 1) << 6;

    // XCD-aware decode: blocks sharing an m-tile have equal g%8 -> same XCD.
    const int g = blockIdx.x;
    const int n_idx = (g >> 3) & ((1 << lognb) - 1);
    const int m_idx = (g & 7) + ((g >> (3 + lognb)) << 3);
    const int n0 = n_idx << 7;
    const u32 m0 = (u32)m_idx << 7;

    // staging: thread covers rows (tid>>3)+32i, LDS slot tid&7; source chunk
    // XOR-swizzled so LDS slot (R, c) holds global chunk c^(R&7).
    const int srow = tid >> 3;
    const int schunk = (tid & 7) ^ (srow & 7);
    const u32 gaoff = (m0 + (u32)srow) * (u32)K + ((u32)schunk << 3);
    const u32 gboff = (u32)(n0 + srow) * (u32)K + ((u32)schunk << 3);

    auto stageA = [&](int kt, int buf) {
        const u16* gak = A + gaoff + (kt << 6);
        u16* la = &As[buf][tid * 8];
#pragma unroll
        for (int i = 0; i < 4; ++i)
            cp_async16(gak + (u32)(i << 5) * (u32)K, la + (i << 11));
    };

    u32x4 breg[4];
    auto loadB = [&](int kt) {
        const u16* gbk = Bt + gboff + (kt << 6);
#pragma unroll
        for (int i = 0; i < 4; ++i)
            breg[i] = *(const u32x4*)(gbk + (u32)(i << 5) * (u32)K);
    };
    auto writeB = [&]() {
        u16* lb = &Bs[tid * 8];
#pragma unroll
        for (int i = 0; i < 4; ++i)
            *(u32x4*)(lb + (i << 11)) = breg[i];
    };

    // fragment read offsets: row R, global chunk j at slot j^(r&7)
    const int cx = (q ^ (r & 7)) << 3;  // elements; ks toggles chunk bit 2
    const int arow = (wm + r) << 6, brow = (wn + r) << 6;

    floatx4 acc[4][4];
#pragma unroll
    for (int mi = 0; mi < 4; ++mi)
#pragma unroll
        for (int ni = 0; ni < 4; ++ni)
            acc[mi][ni] = (floatx4){0.0f, 0.0f, 0.0f, 0.0f};

    const int nk = K >> 6;
    // prologue: tile 0
    loadB(0);
    stageA(0, 0);
    writeB();
    __syncthreads();  // A(0) DMA + B(0) ds_write visible

    for (int kt = 0; kt < nk; ++kt) {
        const int cur = kt & 1;
        const bool pf = (kt + 1 < nk);
        if (pf) {
            loadB(kt + 1);            // into regs, consumed after next barrier
            stageA(kt + 1, cur ^ 1);  // DMA into other buffer, no reg dep
        }
#pragma unroll
        for (int ks = 0; ks < 2; ++ks) {
            half8 af[4], bf[4];
#pragma unroll
            for (int mi = 0; mi < 4; ++mi)
                af[mi] = *(const half8*)&As[cur][arow + (mi << 10) + (cx ^ (ks << 5))];
#pragma unroll
            for (int ni = 0; ni < 4; ++ni)
                bf[ni] = *(const half8*)&Bs[brow + (ni << 10) + (cx ^ (ks << 5))];
#pragma unroll
            for (int mi = 0; mi < 4; ++mi)
#pragma unroll
                for (int ni = 0; ni < 4; ++ni)
                    acc[mi][ni] = __builtin_amdgcn_mfma_f32_16x16x32_f16(
                        af[mi], bf[ni], acc[mi][ni], 0, 0, 0);
        }
        if (pf) {
            __syncthreads();  // all waves done reading Bs(kt); drain overlapped
            writeB();         // Bs <- B(kt+1)
            __syncthreads();  // Bs(kt+1) + As[cur^1] resident
        }
    }

    // epilogue: C/D layout col=lane&15 (=r), row=q*4+reg. Packed-permuted
    // store: stored offset r*4+ni holds actual channel ni*16+r (8B dwordx2).
    float bias_v[4], w0a[4], w0b[4];
#pragma unroll
    for (int ni = 0; ni < 4; ++ni) {
        int col = n0 + wn + ni * 16 + r;
        bias_v[ni] = bias[col];
        w0a[ni] = rel ? w0tail[col] : 0.0f;
        w0b[ni] = rel ? w0tail[N + col] : 0.0f;
    }
#pragma unroll
    for (int mi = 0; mi < 4; ++mi) {
#pragma unroll
        for (int rr = 0; rr < 4; ++rr) {
            u32 row = m0 + wm + mi * 16 + q * 4 + rr;
            float rl0 = 0.0f, rl1 = 0.0f;
            if (rel) {
                rl0 = rel[(size_t)row * 2];
                rl1 = rel[(size_t)row * 2 + 1];
            }
            u32 pk[2];
#pragma unroll
            for (int h = 0; h < 2; ++h) {
                u32 w = 0;
#pragma unroll
                for (int j = 0; j < 2; ++j) {
                    int ni = h * 2 + j;
                    float v = acc[mi][ni][rr] + bias_v[ni];
                    if (rel) v += rl0 * w0a[ni] + rl1 * w0b[ni];
                    v = fmaxf(v, 0.0f);
                    w |= (u32)f2h(v) << (16 * j);
                }
                pk[h] = w;
            }
            *(u32x2*)(C + row * (u32)N + (u32)(n0 + wn + (r << 2))) =
                (u32x2){pk[0], pk[1]};
        }
    }
}

// ---------------- L4 (128 -> 2) + softmax combine ---------------------------
// one wave per point; A3 is packed-permuted -> index W4 through pi()
__global__ __launch_bounds__(256) void l4_combine(
    const u16* __restrict__ A3, const float* __restrict__ W4,
    const float* __restrict__ b4, float* __restrict__ out, int p0) {
    const int wid = threadIdx.x >> 6, lane = threadIdx.x & 63;
    const int pl = blockIdx.x * 4 + wid;
    // stored channels p=2*lane, 2*lane+1 -> actual pi(p)
    const int p2 = lane * 2;
    const int s0 = p2 & 63, bb = p2 & ~63;
    const int k0 = bb + ((s0 & 3) << 4) + (s0 >> 2);
    const int s1 = s0 + 1;
    const int k1 = bb + ((s1 & 3) << 4) + (s1 >> 2);
    const float w00 = W4[k0 * 2], w01 = W4[k0 * 2 + 1];
    const float w10 = W4[k1 * 2], w11 = W4[k1 * 2 + 1];
    float P0[4], P1[4];
#pragma unroll
    for (int s = 0; s < 4; ++s) {
        size_t rowoff = ((size_t)pl * 4 + s) * 128 + p2;
        u32 av = *(const u32*)(A3 + rowoff);
        float a0 = h2f((u16)(av & 0xffffu));
        float a1 = h2f((u16)(av >> 16));
        float d0 = a0 * w00 + a1 * w10;
        float d1 = a0 * w01 + a1 * w11;
#pragma unroll
        for (int m = 32; m >= 1; m >>= 1) {
            d0 += __shfl_xor(d0, m, 64);
            d1 += __shfl_xor(d1, m, 64);
        }
        P0[s] = d0 + b4[0];
        P1[s] = d1 + b4[1];
    }
    if (lane == 0) {
        float mx = fmaxf(fmaxf(P1[0], P1[1]), fmaxf(P1[2], P1[3]));
        float e0 = __expf(P1[0] - mx), e1 = __expf(P1[1] - mx);
        float e2 = __expf(P1[2] - mx), e3 = __expf(P1[3] - mx);
        float se = e0 + e1 + e2 + e3;
        out[p0 + pl] = (P0[0] * e0 + P0[1] * e1 + P0[2] * e2 + P0[3] * e3) / se;
    }
}

// ---------------------------------------------------------------------------
extern "C" void kernel_launch(void* const* d_in, const int* in_sizes, int n_in,
                              void* d_out, int out_size, void* d_ws,
                              size_t ws_size, hipStream_t stream) {
    const float* feat = (const float*)d_in[0];
    const float* coord = (const float*)d_in[1];
    const float* hr = (const float*)d_in[2];
    const float* lr = (const float*)d_in[3];
    const float* W0 = (const float*)d_in[4];
    const float* b0 = (const float*)d_in[5];
    const float* W1 = (const float*)d_in[6];
    const float* b1 = (const float*)d_in[7];
    const float* W2 = (const float*)d_in[8];
    const float* b2 = (const float*)d_in[9];
    const float* W3 = (const float*)d_in[10];
    const float* b3 = (const float*)d_in[11];
    const float* W4 = (const float*)d_in[12];
    const float* b4 = (const float*)d_in[13];
    float* out = (float*)d_out;

    char* base = (char*)d_ws;
    size_t off = 0;
    auto carve = [&](size_t bytes) -> char* {
        char* p = base + off;
        off += (bytes + 255) & ~(size_t)255;
        return p;
    };

    u16* hrT = (u16*)carve(4ull * 65536 * 128 * 2);   // [4][256][256][128] f16
    u16* featT = (u16*)carve(4ull * 4096 * 128 * 2);  // [4][64][64][128] f16
    u16* lrT = (u16*)carve(4ull * 4096 * 128 * 2);
    u16* Wt0 = (u16*)carve(1024ull * 384 * 2);        // [N][K] f16
    u16* Wt1 = (u16*)carve(512ull * 1024 * 2);
    u16* Wt2 = (u16*)carve(256ull * 512 * 2);
    u16* Wt3 = (u16*)carve(128ull * 256 * 2);
    const size_t fixed = off;

    // chunking: per-row footprint with aliasing:
    //   R1 = max(X 768, A1 1024) = 1024 ; rel = 8 ; R2 = A0 2048 >= A2+A3 768
    const size_t R = 1048576ull;  // 262144 points * 4 shifts
    int c = 1;
    for (; c < 8192; c *= 2) {
        size_t Rc = R / c;
        size_t need = fixed;
        size_t sizes[3] = {Rc * 1024, Rc * 8, Rc * 2048};
        for (int i = 0; i < 3; ++i) need += (sizes[i] + 255) & ~(size_t)255;
        if (need <= ws_size) break;
    }
    const size_t Rc = R / c;
    const int Pc = (int)(262144 / c);

    char* R1 = carve(Rc * 1024);
    float* rel = (float*)carve(Rc * 8);
    char* R2 = carve(Rc * 2048);
    u16* X = (u16*)R1;                   // [Rc][384] f16 (dead after L0)
    u16* A1 = (u16*)R1;                  // [Rc][512]  (overwrites X in L1)
    u16* A0 = (u16*)R2;                  // [Rc][1024] (dead after L1)
    u16* A2 = (u16*)R2;                  // [Rc][256]  (overwrites A0 in L2)
    u16* A3 = (u16*)(R2 + Rc * 512);     // [Rc][128]  (disjoint from A2)

    // prep (once per call). W1/W2/W3 get the pi() k-permutation (their A comes
    // from a packed-permuted GEMM output); W0 reads natural-order X.
    transpose_chw_hwc<<<dim3(2048, 4, 4), dim3(32, 8), 0, stream>>>(hr, hrT, 65536);
    transpose_chw_hwc<<<dim3(128, 4, 4), dim3(32, 8), 0, stream>>>(feat, featT, 4096);
    transpose_chw_hwc<<<dim3(128, 4, 4), dim3(32, 8), 0, stream>>>(lr, lrT, 4096);
    prep_wt<<<(1024 * 384 + 255) / 256, 256, 0, stream>>>(W0, Wt0, 384, 1024, 0);
    prep_wt<<<(512 * 1024 + 255) / 256, 256, 0, stream>>>(W1, Wt1, 1024, 512, 1);
    prep_wt<<<(256 * 512 + 255) / 256, 256, 0, stream>>>(W2, Wt2, 512, 256, 1);
    prep_wt<<<(128 * 256 + 255) / 256, 256, 0, stream>>>(W3, Wt3, 256, 128, 1);

    const int mt = (int)(Rc / 128);  // multiple of 8 for all expected c
    for (int ci = 0; ci < c; ++ci) {
        const int p0 = ci * Pc;
        gather_build<<<Pc / 4, 256, 0, stream>>>(coord, hrT, featT, lrT, X, rel, p0);
        gemm_f16<<<mt * 8, 256, 0, stream>>>(X, Wt0, b0, A0, 384, 1024, 3, rel,
                                             W0 + 384 * 1024);
        gemm_f16<<<mt * 4, 256, 0, stream>>>(A0, Wt1, b1, A1, 1024, 512, 2,
                                             nullptr, nullptr);
        gemm_f16<<<mt * 2, 256, 0, stream>>>(A1, Wt2, b2, A2, 512, 256, 1,
                                             nullptr, nullptr);
        gemm_f16<<<mt * 1, 256, 0, stream>>>(A2, Wt3, b3, A3, 256, 128, 0,
                                             nullptr, nullptr);
        l4_combine<<<Pc / 4, 256, 0, stream>>>(A3, W4, b4, out, p0);
    }
}